// Round 6
// baseline (73.452 us; speedup 1.0000x reference)
//
#include <hip/hip_runtime.h>

#define NPRED 300
#define MTGT  64
#define NTHR  256            // 4 waves for cost precompute; wave 0 solves
#define NSLOT 5              // columns per lane: j = k*64 + lane, k = 0..4
#define BIGF  1e30f
#define LDS_FLOATS (MTGT * NPRED + 64)   // +64 pad so k=4 reads never go OOB

// Exact IEEE f32 op order matching the jax/numpy reference (no FMA contraction).
__device__ __forceinline__ float cost_ij(float p0, float p1, float p2, float p3,
                                         float t0, float t1, float t2, float t3)
{
    float area_p = __fmul_rn(__fsub_rn(p2, p0), __fsub_rn(p3, p1));
    float area_t = __fmul_rn(__fsub_rn(t2, t0), __fsub_rn(t3, t1));
    float cb = fabsf(__fsub_rn(p0, t0));
    cb = __fadd_rn(cb, fabsf(__fsub_rn(p1, t1)));
    cb = __fadd_rn(cb, fabsf(__fsub_rn(p2, t2)));
    cb = __fadd_rn(cb, fabsf(__fsub_rn(p3, t3)));
    float ltx = fmaxf(p0, t0), lty = fmaxf(p1, t1);
    float rbx = fminf(p2, t2), rby = fminf(p3, t3);
    float w = fmaxf(__fsub_rn(rbx, ltx), 0.0f);
    float h = fmaxf(__fsub_rn(rby, lty), 0.0f);
    float inter = __fmul_rn(w, h);
    float uni = __fsub_rn(__fadd_rn(area_p, area_t), inter);
    float iou = __fdiv_rn(inter, __fadd_rn(uni, 1e-7f));
    return __fadd_rn(__fmul_rn(5.0f, cb), __fmul_rn(2.0f, -iou));
}

// 64-lane min via single-instruction DPP v_min_f32. BC=0 (default): lanes with
// an invalid DPP source do not write the dest -> keep their own value, which is
// exactly the min identity. HAZARD: DPP reading a VGPR written by the previous
// VALU op needs 2 wait states -> s_nop 1 between steps AND at both asm
// boundaries (the compiler cannot see inside the asm to insert them).
__device__ __forceinline__ float dpp_min6(float x)
{
    asm("s_nop 1\n\t"
        "v_min_f32 %0, %0, %0 row_shr:1\n\t"
        "s_nop 1\n\t"
        "v_min_f32 %0, %0, %0 row_shr:2\n\t"
        "s_nop 1\n\t"
        "v_min_f32 %0, %0, %0 row_shr:4\n\t"
        "s_nop 1\n\t"
        "v_min_f32 %0, %0, %0 row_shr:8\n\t"
        "s_nop 1\n\t"
        "v_min_f32 %0, %0, %0 row_bcast:15\n\t"
        "s_nop 1\n\t"
        "v_min_f32 %0, %0, %0 row_bcast:31\n\t"
        "s_nop 1"
        : "+v"(x));
    return x;
}

template<int CTRL>
__device__ __forceinline__ unsigned dppminu(unsigned x)
{
    unsigned m = (unsigned)__builtin_amdgcn_update_dpp(0x7FFFFFFF, (int)x,
                                                       CTRL, 0xF, 0xF, false);
    return x < m ? x : m;
}

__device__ __forceinline__ float readlane_f(float x, int l)
{
    return __int_as_float(__builtin_amdgcn_readlane(__float_as_int(x), l));
}

__global__ __launch_bounds__(NTHR)
void hungarian_kernel(const float* __restrict__ pred,   // [B, NPRED, 4]
                      const float* __restrict__ tgt,    // [B, MTGT, 4]
                      const int*   __restrict__ mask,   // [B, MTGT]
                      int* __restrict__ out,            // [2, B, MTGT]
                      int B)
{
    extern __shared__ float Cmat[];        // [MTGT][NPRED] + pad
    const int b   = blockIdx.x;
    const int tid = threadIdx.x;

    const float* pb_base = pred + (size_t)b * NPRED * 4;
    const float* tb_base = tgt  + (size_t)b * MTGT  * 4;
    const int*   mk      = mask + (size_t)b * MTGT;

    // ---- precompute cost matrix with all 4 waves (75 entries/thread) ----
    for (int e = tid; e < MTGT * NPRED; e += NTHR) {
        int i = e / NPRED;
        int j = e - i * NPRED;
        const float* pb = pb_base + j * 4;
        const float* tb = tb_base + i * 4;
        float c = cost_ij(pb[0], pb[1], pb[2], pb[3], tb[0], tb[1], tb[2], tb[3]);
        Cmat[e] = (mk[i] > 0) ? c : 0.0f;
    }
    if (tid < 64) Cmat[MTGT * NPRED + tid] = 0.0f;   // zero the pad
    __syncthreads();
    if (tid >= 64) return;                 // waves 1-3 done; no barriers below

    // ================= single-wave solver: lane = tid =================
    const int lane = tid;
    const int vm   = mk[lane] > 0;
    const float* cbase = Cmat + lane;      // per-lane column base

    float vdual[NSLOT];                    // v[j] for j = k*64+lane
    float sh[NSLOT];                       // shortest[j]
    int   pth[NSLOT];                      // path[j]
    int   r4c1[NSLOT];                     // row4col[j]+1 (0 = free)
    #pragma unroll
    for (int k = 0; k < NSLOT; ++k) { vdual[k] = 0.0f; r4c1[k] = 0; }
    float u   = 0.0f;                      // u[row=lane]
    int   c4r = -1;                        // col4row[row=lane]

    const int sc_init = (lane < (NPRED - 4 * 64)) ? 0 : (1 << 4);  // j>=300 dead

    // prefetched cost row (always holds costs of the row the next pop relaxes)
    float c0, c1, c2, c3, c4;
    #define LOAD_ROW(ii) do { const float* cr_ = cbase + (ii) * NPRED;        \
        c0 = cr_[0]; c1 = cr_[64]; c2 = cr_[128]; c3 = cr_[192]; c4 = cr_[256];\
    } while (0)

    LOAD_ROW(0);                           // row 0, first pop

    for (int cur_row = 0; cur_row < MTGT; ++cur_row) {
        #pragma unroll
        for (int k = 0; k < NSLOT; ++k) { sh[k] = BIGF; pth[k] = -1; }
        int   SCm    = sc_init;
        int   SRb    = 0;
        float minVal = 0.0f;               // lane-uniform
        int   i      = cur_row;            // lane-uniform (scalar)
        int   sink;

        for (;;) {
            const float u_i = readlane_f(u, i);
            SRb |= (lane == i);

            // ---- old-shortest tree (independent of the pending loads)
            // aux = (k<<8) | (owner+1); smaller aux == smaller j for distinct k
            float vo; unsigned ao;
            {
                float a0 = (SCm & 1)  ? BIGF : sh[0];
                float a1 = (SCm & 2)  ? BIGF : sh[1];
                float a2 = (SCm & 4)  ? BIGF : sh[2];
                float a3 = (SCm & 8)  ? BIGF : sh[3];
                float a4 = (SCm & 16) ? BIGF : sh[4];
                float m01 = a0; unsigned q01 = (0u << 8) | (unsigned)r4c1[0];
                if (a1 < m01) { m01 = a1; q01 = (1u << 8) | (unsigned)r4c1[1]; }
                float m23 = a2; unsigned q23 = (2u << 8) | (unsigned)r4c1[2];
                if (a3 < m23) { m23 = a3; q23 = (3u << 8) | (unsigned)r4c1[3]; }
                vo = m01; ao = q01;
                if (m23 < vo) { vo = m23; ao = q23; }
                if (a4 < vo) { vo = a4; ao = (4u << 8) | (unsigned)r4c1[4]; }
            }

            // ---- relax with the prefetched costs (exact reference op order)
            float r0 = __fsub_rn(__fsub_rn(__fadd_rn(minVal, c0), u_i), vdual[0]);
            float r1 = __fsub_rn(__fsub_rn(__fadd_rn(minVal, c1), u_i), vdual[1]);
            float r2 = __fsub_rn(__fsub_rn(__fadd_rn(minVal, c2), u_i), vdual[2]);
            float r3 = __fsub_rn(__fsub_rn(__fadd_rn(minVal, c3), u_i), vdual[3]);
            float r4 = __fsub_rn(__fsub_rn(__fadd_rn(minVal, c4), u_i), vdual[4]);
            float rr[NSLOT] = { r0, r1, r2, r3, r4 };
            float cr[NSLOT];
            #pragma unroll
            for (int k = 0; k < NSLOT; ++k) {
                bool act = !((SCm >> k) & 1);
                bool upd = act && (rr[k] < sh[k]);
                sh[k]  = upd ? rr[k] : sh[k];
                pth[k] = upd ? i : pth[k];
                cr[k]  = act ? rr[k] : BIGF;
            }
            // new-r tree (k ascending; keep-first on tie)
            float nv; unsigned na;
            {
                float m01 = cr[0]; unsigned q01 = (0u << 8) | (unsigned)r4c1[0];
                if (cr[1] < m01) { m01 = cr[1]; q01 = (1u << 8) | (unsigned)r4c1[1]; }
                float m23 = cr[2]; unsigned q23 = (2u << 8) | (unsigned)r4c1[2];
                if (cr[3] < m23) { m23 = cr[3]; q23 = (3u << 8) | (unsigned)r4c1[3]; }
                nv = m01; na = q01;
                if (m23 < nv) { nv = m23; na = q23; }
                if (cr[4] < nv) { nv = cr[4]; na = (4u << 8) | (unsigned)r4c1[4]; }
            }
            // merge old/new (lex on (val, aux) — aux order == j order)
            bool tn = (nv < vo) || (nv == vo && na < ao);
            float    vt = tn ? nv : vo;
            unsigned at = tn ? na : ao;

            // ---- 64-lane value-only DPP min (hazard-safe fused steps) ----
            const float mv = readlane_f(dpp_min6(vt), 63);

            // ---- winner lane + (k, owner) recovery ----
            unsigned long long eqm = __ballot(vt == mv);
            int wl, kown;
            if (__builtin_expect(__popcll(eqm) == 1, 1)) {  // unique min
                wl   = (int)__builtin_ctzll(eqm);
                kown = __builtin_amdgcn_readlane((int)at, wl);
            } else {                                        // exact-tie slow path
                unsigned bjc = (vt == mv) ? (((at >> 8) << 6) | (unsigned)lane)
                                          : 0x7FFFFFFFu;
                bjc = dppminu<0x111>(bjc);
                bjc = dppminu<0x112>(bjc);
                bjc = dppminu<0x114>(bjc);
                bjc = dppminu<0x118>(bjc);
                bjc = dppminu<0x142>(bjc);
                bjc = dppminu<0x143>(bjc);
                int bj = __builtin_amdgcn_readlane((int)bjc, 63);
                wl   = bj & 63;
                kown = __builtin_amdgcn_readlane((int)at, wl);
            }
            const int kw = kown >> 8;          // winning slot k
            const int ow = kown & 0xFF;        // row4col[bj]+1 (0 = free)
            const int bj = (kw << 6) | wl;     // winning column j

            minVal = mv;
            // SC[bj] = true
            int nb = SCm | (1 << kw);
            SCm = (lane == wl) ? nb : SCm;

            if (ow == 0) {                     // free column: row done
                sink = bj;
                int nr = cur_row + 1;          // prefetch next row's costs so
                if (nr >= MTGT) nr = MTGT - 1; // the LDS wait hides under the
                LOAD_ROW(nr);                  // dual-update + augment tail
                break;
            }
            i = ow - 1;                        // continue from its owner row
            LOAD_ROW(i);                       // issue loads ASAP (bottom)
        }

        // ---- dual updates ----
        {
            int c  = c4r < 0 ? 0 : c4r;                 // clip(col4row, 0)
            int cl = c & 63, cs = c >> 6;
            float g[NSLOT];
            #pragma unroll
            for (int k = 0; k < NSLOT; ++k) g[k] = __shfl(sh[k], cl);
            float sv = cs == 0 ? g[0] : cs == 1 ? g[1] : cs == 2 ? g[2]
                     : cs == 3 ? g[3] : g[4];
            if (lane == cur_row)      u = __fadd_rn(u, minVal);
            else if (SRb)             u = __fadd_rn(u, __fsub_rn(minVal, sv));
            #pragma unroll
            for (int k = 0; k < NSLOT; ++k) {
                const int j = k * 64 + lane;
                if (j < NPRED && ((SCm >> k) & 1))
                    vdual[k] = __fsub_rn(vdual[k], __fsub_rn(minVal, sh[k]));
            }
        }

        // ---- augment along alternating path (uniform, readlane-based) ----
        {
            int j  = sink;
            int ia = -1;
            while (ia != cur_row) {
                int jl = j & 63, js = j >> 6;
                int p0r = __builtin_amdgcn_readlane(pth[0], jl);
                int p1r = __builtin_amdgcn_readlane(pth[1], jl);
                int p2r = __builtin_amdgcn_readlane(pth[2], jl);
                int p3r = __builtin_amdgcn_readlane(pth[3], jl);
                int p4r = __builtin_amdgcn_readlane(pth[4], jl);
                ia = js == 0 ? p0r : js == 1 ? p1r : js == 2 ? p2r
                   : js == 3 ? p3r : p4r;
                // row4col[j] = ia  (per-lane replicated table, +1 encoding)
                #pragma unroll
                for (int k = 0; k < NSLOT; ++k) {
                    bool sel = (js == k) && (lane == jl);
                    r4c1[k] = sel ? (ia + 1) : r4c1[k];
                }
                int jn = __builtin_amdgcn_readlane(c4r, ia);   // old col4row[ia]
                if (lane == ia) c4r = j;
                j = jn;
            }
        }
    }
    #undef LOAD_ROW

    out[(size_t)b * MTGT + lane]                    = vm ? c4r : -1;
    out[(size_t)B * MTGT + (size_t)b * MTGT + lane] = vm ? lane : -1;
}

extern "C" void kernel_launch(void* const* d_in, const int* in_sizes, int n_in,
                              void* d_out, int out_size, void* d_ws, size_t ws_size,
                              hipStream_t stream)
{
    const float* pred = (const float*)d_in[0];
    const float* tgt  = (const float*)d_in[1];
    const int*   mask = (const int*)d_in[2];
    int* out = (int*)d_out;

    const int B = in_sizes[2] / MTGT;   // mask is [B, MTGT]
    const size_t lds_bytes = LDS_FLOATS * sizeof(float);   // 77 KB > 64 KB: opt in

    (void)hipFuncSetAttribute((const void*)hungarian_kernel,
                              hipFuncAttributeMaxDynamicSharedMemorySize,
                              (int)lds_bytes);

    hipLaunchKernelGGL(hungarian_kernel, dim3(B), dim3(NTHR), lds_bytes, stream,
                       pred, tgt, mask, out, B);
}

// Round 7
// 65.165 us; speedup vs baseline: 1.1272x; 1.1272x over previous
//
#include <hip/hip_runtime.h>

#define NPRED 300
#define MTGT  64
#define NTHR  256            // 4 waves for cost precompute; wave 0 solves
#define NSLOT 5              // columns per lane: j = k*64 + lane, k = 0..4
#define BIGF  1e30f
#define LDS_FLOATS (MTGT * NPRED + 64)   // +64 pad so k=4 reads never go OOB

// Exact IEEE f32 op order matching the jax/numpy reference (no FMA contraction).
__device__ __forceinline__ float cost_ij(float p0, float p1, float p2, float p3,
                                         float t0, float t1, float t2, float t3)
{
    float area_p = __fmul_rn(__fsub_rn(p2, p0), __fsub_rn(p3, p1));
    float area_t = __fmul_rn(__fsub_rn(t2, t0), __fsub_rn(t3, t1));
    float cb = fabsf(__fsub_rn(p0, t0));
    cb = __fadd_rn(cb, fabsf(__fsub_rn(p1, t1)));
    cb = __fadd_rn(cb, fabsf(__fsub_rn(p2, t2)));
    cb = __fadd_rn(cb, fabsf(__fsub_rn(p3, t3)));
    float ltx = fmaxf(p0, t0), lty = fmaxf(p1, t1);
    float rbx = fminf(p2, t2), rby = fminf(p3, t3);
    float w = fmaxf(__fsub_rn(rbx, ltx), 0.0f);
    float h = fmaxf(__fsub_rn(rby, lty), 0.0f);
    float inter = __fmul_rn(w, h);
    float uni = __fsub_rn(__fadd_rn(area_p, area_t), inter);
    float iou = __fdiv_rn(inter, __fadd_rn(uni, 1e-7f));
    return __fadd_rn(__fmul_rn(5.0f, cb), __fmul_rn(2.0f, -iou));
}

// 64-lane min via single-instruction DPP v_min_f32. BC=0 (default): lanes with
// an invalid DPP source do not write the dest -> keep their own value, which is
// exactly the min identity. HAZARD: DPP reading a VGPR written by the previous
// VALU op needs 2 wait states -> s_nop 1 between steps AND at both asm
// boundaries (the compiler cannot see inside the asm to insert them).
__device__ __forceinline__ float dpp_min6(float x)
{
    asm("s_nop 1\n\t"
        "v_min_f32 %0, %0, %0 row_shr:1\n\t"
        "s_nop 1\n\t"
        "v_min_f32 %0, %0, %0 row_shr:2\n\t"
        "s_nop 1\n\t"
        "v_min_f32 %0, %0, %0 row_shr:4\n\t"
        "s_nop 1\n\t"
        "v_min_f32 %0, %0, %0 row_shr:8\n\t"
        "s_nop 1\n\t"
        "v_min_f32 %0, %0, %0 row_bcast:15\n\t"
        "s_nop 1\n\t"
        "v_min_f32 %0, %0, %0 row_bcast:31\n\t"
        "s_nop 1"
        : "+v"(x));
    return x;
}

template<int CTRL>
__device__ __forceinline__ unsigned dppminu(unsigned x)
{
    unsigned m = (unsigned)__builtin_amdgcn_update_dpp(0x7FFFFFFF, (int)x,
                                                       CTRL, 0xF, 0xF, false);
    return x < m ? x : m;
}

__device__ __forceinline__ float readlane_f(float x, int l)
{
    return __int_as_float(__builtin_amdgcn_readlane(__float_as_int(x), l));
}

__global__ __launch_bounds__(NTHR)
void hungarian_kernel(const float* __restrict__ pred,   // [B, NPRED, 4]
                      const float* __restrict__ tgt,    // [B, MTGT, 4]
                      const int*   __restrict__ mask,   // [B, MTGT]
                      int* __restrict__ out,            // [2, B, MTGT]
                      int B)
{
    extern __shared__ float Cmat[];        // [MTGT][NPRED] + pad
    const int b   = blockIdx.x;
    const int tid = threadIdx.x;

    const float* pb_base = pred + (size_t)b * NPRED * 4;
    const float* tb_base = tgt  + (size_t)b * MTGT  * 4;
    const int*   mk      = mask + (size_t)b * MTGT;

    // ---- precompute cost matrix with all 4 waves (75 entries/thread) ----
    for (int e = tid; e < MTGT * NPRED; e += NTHR) {
        int i = e / NPRED;
        int j = e - i * NPRED;
        const float* pb = pb_base + j * 4;
        const float* tb = tb_base + i * 4;
        float c = cost_ij(pb[0], pb[1], pb[2], pb[3], tb[0], tb[1], tb[2], tb[3]);
        Cmat[e] = (mk[i] > 0) ? c : 0.0f;
    }
    if (tid < 64) Cmat[MTGT * NPRED + tid] = 0.0f;   // zero the pad
    __syncthreads();
    if (tid >= 64) return;                 // waves 1-3 done; no barriers below

    // ================= single-wave solver: lane = tid =================
    const int lane = tid;
    const int vm   = mk[lane] > 0;
    const float* cbase = Cmat + lane;      // per-lane column base

    float vdual[NSLOT];                    // v[j] for j = k*64+lane
    float sh[NSLOT];                       // shortest[j]
    int   pth[NSLOT];                      // path[j]
    int   r4c1[NSLOT];                     // row4col[j]+1 (0 = free)
    #pragma unroll
    for (int k = 0; k < NSLOT; ++k) { vdual[k] = 0.0f; r4c1[k] = 0; }
    float u   = 0.0f;                      // u[row=lane]
    int   c4r = -1;                        // col4row[row=lane]
    float sv_reg = 0.0f;                   // shortest[col4row[lane]] at pull-in

    const int sc_init = (lane < (NPRED - 4 * 64)) ? 0 : (1 << 4);  // j>=300 dead

    // prefetched cost row (always holds costs of the row the next pop relaxes)
    float c0, c1, c2, c3, c4;
    #define LOAD_ROW(ii) do { const float* cr_ = cbase + (ii) * NPRED;        \
        c0 = cr_[0]; c1 = cr_[64]; c2 = cr_[128]; c3 = cr_[192]; c4 = cr_[256];\
    } while (0)

    LOAD_ROW(0);                           // row 0, first pop

    for (int cur_row = 0; cur_row < MTGT; ++cur_row) {
        #pragma unroll
        for (int k = 0; k < NSLOT; ++k) { sh[k] = BIGF; pth[k] = -1; }
        int   SCm    = sc_init;
        int   pulled = 0;                  // this row iter: lane's row pulled in
        float minVal = 0.0f;               // lane-uniform
        int   i      = cur_row;            // lane-uniform (scalar)
        int   sink;

        for (;;) {
            const float u_i = readlane_f(u, i);

            // ---- old-shortest tree (independent of the pending loads)
            // aux = (k<<8) | (owner+1); smaller aux == smaller j for distinct k
            float vo; unsigned ao;
            {
                float a0 = (SCm & 1)  ? BIGF : sh[0];
                float a1 = (SCm & 2)  ? BIGF : sh[1];
                float a2 = (SCm & 4)  ? BIGF : sh[2];
                float a3 = (SCm & 8)  ? BIGF : sh[3];
                float a4 = (SCm & 16) ? BIGF : sh[4];
                float m01 = a0; unsigned q01 = (0u << 8) | (unsigned)r4c1[0];
                if (a1 < m01) { m01 = a1; q01 = (1u << 8) | (unsigned)r4c1[1]; }
                float m23 = a2; unsigned q23 = (2u << 8) | (unsigned)r4c1[2];
                if (a3 < m23) { m23 = a3; q23 = (3u << 8) | (unsigned)r4c1[3]; }
                vo = m01; ao = q01;
                if (m23 < vo) { vo = m23; ao = q23; }
                if (a4 < vo) { vo = a4; ao = (4u << 8) | (unsigned)r4c1[4]; }
            }

            // ---- relax with the prefetched costs (exact reference op order)
            float r0 = __fsub_rn(__fsub_rn(__fadd_rn(minVal, c0), u_i), vdual[0]);
            float r1 = __fsub_rn(__fsub_rn(__fadd_rn(minVal, c1), u_i), vdual[1]);
            float r2 = __fsub_rn(__fsub_rn(__fadd_rn(minVal, c2), u_i), vdual[2]);
            float r3 = __fsub_rn(__fsub_rn(__fadd_rn(minVal, c3), u_i), vdual[3]);
            float r4 = __fsub_rn(__fsub_rn(__fadd_rn(minVal, c4), u_i), vdual[4]);
            float rr[NSLOT] = { r0, r1, r2, r3, r4 };
            float cr[NSLOT];
            #pragma unroll
            for (int k = 0; k < NSLOT; ++k) {
                bool act = !((SCm >> k) & 1);
                bool upd = act && (rr[k] < sh[k]);
                sh[k]  = upd ? rr[k] : sh[k];
                pth[k] = upd ? i : pth[k];
                cr[k]  = act ? rr[k] : BIGF;
            }
            // new-r tree (k ascending; keep-first on tie)
            float nv; unsigned na;
            {
                float m01 = cr[0]; unsigned q01 = (0u << 8) | (unsigned)r4c1[0];
                if (cr[1] < m01) { m01 = cr[1]; q01 = (1u << 8) | (unsigned)r4c1[1]; }
                float m23 = cr[2]; unsigned q23 = (2u << 8) | (unsigned)r4c1[2];
                if (cr[3] < m23) { m23 = cr[3]; q23 = (3u << 8) | (unsigned)r4c1[3]; }
                nv = m01; na = q01;
                if (m23 < nv) { nv = m23; na = q23; }
                if (cr[4] < nv) { nv = cr[4]; na = (4u << 8) | (unsigned)r4c1[4]; }
            }
            // merge old/new (lex on (val, aux) — aux order == j order)
            bool tn = (nv < vo) || (nv == vo && na < ao);
            float    vt = tn ? nv : vo;
            unsigned at = tn ? na : ao;

            // ---- 64-lane value-only DPP min (hazard-safe fused steps) ----
            const float mv = readlane_f(dpp_min6(vt), 63);

            // ---- winner lane + (k, owner) recovery ----
            unsigned long long eqm = __ballot(vt == mv);
            int wl, kown;
            if (__builtin_expect(__popcll(eqm) == 1, 1)) {  // unique min
                wl   = (int)__builtin_ctzll(eqm);
                kown = __builtin_amdgcn_readlane((int)at, wl);
            } else {                                        // exact-tie slow path
                unsigned bjc = (vt == mv) ? (((at >> 8) << 6) | (unsigned)lane)
                                          : 0x7FFFFFFFu;
                bjc = dppminu<0x111>(bjc);
                bjc = dppminu<0x112>(bjc);
                bjc = dppminu<0x114>(bjc);
                bjc = dppminu<0x118>(bjc);
                bjc = dppminu<0x142>(bjc);
                bjc = dppminu<0x143>(bjc);
                int bj = __builtin_amdgcn_readlane((int)bjc, 63);
                wl   = bj & 63;
                kown = __builtin_amdgcn_readlane((int)at, wl);
            }
            const int kw = kown >> 8;          // winning slot k
            const int ow = kown & 0xFF;        // row4col[bj]+1 (0 = free)
            const int bj = (kw << 6) | wl;     // winning column j

            minVal = mv;
            // SC[bj] = true
            int nb = SCm | (1 << kw);
            SCm = (lane == wl) ? nb : SCm;

            if (ow == 0) {                     // free column: row done
                sink = bj;
                int nr = cur_row + 1;          // prefetch next row's costs so
                if (nr >= MTGT) nr = MTGT - 1; // the LDS wait hides under the
                LOAD_ROW(nr);                  // dual-update + augment tail
                break;
            }
            i = ow - 1;                        // continue from its owner row
            // Row i pulled into SR: record shortest[col4row[i]] == mv (frozen
            // the moment SC[bj] was set; col4row unchanged until augmentation).
            if (lane == i) { sv_reg = mv; pulled = 1; }
            LOAD_ROW(i);                       // issue loads ASAP
        }

        // ---- dual updates (pure per-lane register math, no cross-lane) ----
        if (lane == cur_row)      u = __fadd_rn(u, minVal);
        else if (pulled)          u = __fadd_rn(u, __fsub_rn(minVal, sv_reg));
        #pragma unroll
        for (int k = 0; k < NSLOT; ++k) {
            const int j = k * 64 + lane;
            if (j < NPRED && ((SCm >> k) & 1))
                vdual[k] = __fsub_rn(vdual[k], __fsub_rn(minVal, sh[k]));
        }

        // ---- augment along alternating path (uniform, readlane-based) ----
        {
            int j  = sink;
            int ia = -1;
            while (ia != cur_row) {
                int jl = j & 63, js = j >> 6;
                int p0r = __builtin_amdgcn_readlane(pth[0], jl);
                int p1r = __builtin_amdgcn_readlane(pth[1], jl);
                int p2r = __builtin_amdgcn_readlane(pth[2], jl);
                int p3r = __builtin_amdgcn_readlane(pth[3], jl);
                int p4r = __builtin_amdgcn_readlane(pth[4], jl);
                ia = js == 0 ? p0r : js == 1 ? p1r : js == 2 ? p2r
                   : js == 3 ? p3r : p4r;
                // row4col[j] = ia  (per-lane replicated table, +1 encoding)
                #pragma unroll
                for (int k = 0; k < NSLOT; ++k) {
                    bool sel = (js == k) && (lane == jl);
                    r4c1[k] = sel ? (ia + 1) : r4c1[k];
                }
                int jn = __builtin_amdgcn_readlane(c4r, ia);   // old col4row[ia]
                if (lane == ia) c4r = j;
                j = jn;
            }
        }
    }
    #undef LOAD_ROW

    out[(size_t)b * MTGT + lane]                    = vm ? c4r : -1;
    out[(size_t)B * MTGT + (size_t)b * MTGT + lane] = vm ? lane : -1;
}

extern "C" void kernel_launch(void* const* d_in, const int* in_sizes, int n_in,
                              void* d_out, int out_size, void* d_ws, size_t ws_size,
                              hipStream_t stream)
{
    const float* pred = (const float*)d_in[0];
    const float* tgt  = (const float*)d_in[1];
    const int*   mask = (const int*)d_in[2];
    int* out = (int*)d_out;

    const int B = in_sizes[2] / MTGT;   // mask is [B, MTGT]
    const size_t lds_bytes = LDS_FLOATS * sizeof(float);   // 77 KB > 64 KB: opt in

    (void)hipFuncSetAttribute((const void*)hungarian_kernel,
                              hipFuncAttributeMaxDynamicSharedMemorySize,
                              (int)lds_bytes);

    hipLaunchKernelGGL(hungarian_kernel, dim3(B), dim3(NTHR), lds_bytes, stream,
                       pred, tgt, mask, out, B);
}